// Round 10
// baseline (338.270 us; speedup 1.0000x reference)
//
#include <hip/hip_runtime.h>
#include <math.h>

#define NUM_GROUPS 100
#define GROUP_SIZE 100
#define TOTAL_ROWS 10000
#define NUM_CLASSES 1000
#define BATCH 4096
#define SPB 4                      // samples per gather block (1 wave each)
#define GATHER_BLOCKS (BATCH / SPB)   // 1024 = 4 blocks/CU = ONE generation
#define NSLICE 5
#define SLICE_ROWS (GROUP_SIZE / NSLICE)   // 20
#define ROW_U2 256                 // padded row: 1024 bf16 = 256 uint2 = 128 uint4
#define EXTRACT_BLOCKS 2500
#define PREP_BLOCKS (NUM_GROUPS * NSLICE)  // 500

// bf16 helpers: pack with RTNE, unpack via shift (bf16->fp32 is exact)
__device__ __forceinline__ unsigned int f2bf(float f) {
    unsigned int u = __float_as_uint(f);
    return (u + 0x7FFFu + ((u >> 16) & 1u)) >> 16;
}
__device__ __forceinline__ float bflo(unsigned int p) { return __uint_as_float(p << 16); }
__device__ __forceinline__ float bfhi(unsigned int p) { return __uint_as_float(p & 0xFFFF0000u); }

// ---------------------------------------------------------------------------
// k_stage: prep + extract merged into one 3000-block grid so the two
// independent memory phases overlap (extract streams 164 MB HBM while prep
// blocks do exp/pack on 40 MB). Extract role first (long pole).
//  - extract (blocks 0..2499): idxB[b*100+g] = active global row id.
//  - prep (blocks 2500..2999): streaming exp-sum (no max: xavier |W|<0.1)
//    + bf16 pack into rows PADDED to 1024 classes (zeroed pad).
// ---------------------------------------------------------------------------
__global__ __launch_bounds__(256)
void k_stage(const float* __restrict__ W, const float* __restrict__ x,
             float* __restrict__ Sp, unsigned int* __restrict__ Wh,
             int* __restrict__ idxB) {
    const int bid = blockIdx.x;
    const int tid = threadIdx.x;

    if (bid < EXTRACT_BLOCKS) {
        // ---------------- extract role ----------------
        const float4* x4 = (const float4*)x;
        const int base = bid * 4096 + tid;
        #pragma unroll
        for (int k0 = 0; k0 < 16; k0 += 8) {
            float4 v[8];
            #pragma unroll
            for (int u = 0; u < 8; ++u)
                v[u] = x4[base + (k0 + u) * 256];
            #pragma unroll
            for (int u = 0; u < 8; ++u) {
                float4 vv = v[u];
                if (vv.x > 0.5f || vv.y > 0.5f || vv.z > 0.5f || vv.w > 0.5f) {
                    int i  = base + (k0 + u) * 256;
                    int b  = i / 2500;
                    int r4 = i - b * 2500;
                    int g  = r4 / 25;             // float4 never crosses a group
                    int j  = r4 * 4;
                    int val = vv.x > 0.5f ? j
                            : (vv.y > 0.5f ? j + 1 : (vv.z > 0.5f ? j + 2 : j + 3));
                    idxB[b * NUM_GROUPS + g] = val;
                }
            }
        }
    } else {
        // ---------------- prep role ----------------
        const int pid = bid - EXTRACT_BLOCKS;     // 0..499
        const int g   = pid / NSLICE;
        const int h   = pid % NSLICE;
        const int r0  = h * SLICE_ROWS;

        const float4* Wr = (const float4*)(W + (size_t)(g * GROUP_SIZE + r0) * NUM_CLASSES);
        uint2* Whr = (uint2*)Wh + (size_t)(g * GROUP_SIZE + r0) * ROW_U2;

        if (tid < 250) {
            float4 s = make_float4(0.f, 0.f, 0.f, 0.f);
            #pragma unroll
            for (int k0 = 0; k0 < SLICE_ROWS; k0 += 5) {
                float4 v[5];
                #pragma unroll
                for (int u = 0; u < 5; ++u)
                    v[u] = Wr[(size_t)(k0 + u) * 250 + tid];
                #pragma unroll
                for (int u = 0; u < 5; ++u) {
                    float4 vv = v[u];
                    s.x += __expf(vv.x); s.y += __expf(vv.y);
                    s.z += __expf(vv.z); s.w += __expf(vv.w);
                    Whr[(size_t)(k0 + u) * ROW_U2 + tid] =
                        make_uint2(f2bf(vv.x) | (f2bf(vv.y) << 16),
                                   f2bf(vv.z) | (f2bf(vv.w) << 16));
                }
            }
            *(float4*)(Sp + (size_t)(g * NSLICE + h) * NUM_CLASSES + tid * 4) = s;
        }
        // zero the 6 pad uint2 (classes 1000..1023) of each of the 20 rows
        if (tid < SLICE_ROWS * 6) {
            int r = tid / 6, p = 250 + tid % 6;
            Whr[(size_t)r * ROW_U2 + p] = make_uint2(0u, 0u);
        }
    }
}

// ---------------------------------------------------------------------------
// k_combine: base[c] = bias[c] - sum_g log(sum_h Sp[g,h,c]).
// ---------------------------------------------------------------------------
__global__ __launch_bounds__(256)
void k_combine(const float* __restrict__ Sp, const float* __restrict__ bias,
               float* __restrict__ base) {
    const int c = blockIdx.x * 250 + threadIdx.x;
    if (threadIdx.x >= 250 || c >= NUM_CLASSES) return;
    float acc = bias[c];
    #pragma unroll 4
    for (int g = 0; g < NUM_GROUPS; ++g) {
        const float* p = Sp + (size_t)g * NSLICE * NUM_CLASSES + c;
        float S = p[0];
        #pragma unroll
        for (int h = 1; h < NSLICE; ++h) S += p[h * NUM_CLASSES];
        acc -= __logf(S);
    }
    base[c] = acc;
}

// ---------------------------------------------------------------------------
// k_gather: 1024 blocks x 4 samples, one wave per sample, NO LDS/barriers.
// All 100 row ids live in two VGPRs (lane l: id l and id 64+l); the fully
// unrolled group loop broadcasts them with readlane(reg, CONST) -> pure
// SGPR dependency, no ds_read in the hot loop, deep load pipelining.
// Lane l owns classes 8l..8l+7 and 512+8l..512+8l+7 (padded 1024-class rows).
// Epilogue: shfl_xor butterfly softmax; pad lanes (61-63 chunk1) masked.
// ---------------------------------------------------------------------------
__global__ __launch_bounds__(256, 4)
void k_gather(const int* __restrict__ idxB, const uint4* __restrict__ Wh4,
              const float* __restrict__ base, float* __restrict__ out) {
    const int tid = threadIdx.x;
    const int w = tid >> 6;                       // wave = sample
    const int l = tid & 63;
    const int b0 = blockIdx.x * SPB;
    const bool real1 = (l <= 60);                 // chunk1 lanes 61-63 are pad

    // stage this sample's 100 row-ids into 2 VGPRs (coalesced dword loads)
    const int* myidx = idxB + (size_t)(b0 + w) * NUM_GROUPS;
    const int idxlo = myidx[l];                            // groups 0..63
    const int idxhi = myidx[(l < 36) ? (64 + l) : 63];     // groups 64..99

    float acc[16];
    #pragma unroll
    for (int k = 0; k < 16; ++k) acc[k] = 0.0f;

    #pragma unroll
    for (int g = 0; g < NUM_GROUPS; g += 4) {
        uint4 v[4][2];
        #pragma unroll
        for (int u = 0; u < 4; ++u) {
            const int gg = g + u;                 // compile-time constant
            int r = (gg < 64) ? __builtin_amdgcn_readlane(idxlo, gg)
                              : __builtin_amdgcn_readlane(idxhi, gg - 64);
            const uint4* row = Wh4 + (size_t)r * 128;
            v[u][0] = row[l];
            v[u][1] = row[l + 64];
        }
        #pragma unroll
        for (int u = 0; u < 4; ++u) {
            #pragma unroll
            for (int hh = 0; hh < 2; ++hh) {
                acc[hh * 8 + 0] += bflo(v[u][hh].x);
                acc[hh * 8 + 1] += bfhi(v[u][hh].x);
                acc[hh * 8 + 2] += bflo(v[u][hh].y);
                acc[hh * 8 + 3] += bfhi(v[u][hh].y);
                acc[hh * 8 + 4] += bflo(v[u][hh].z);
                acc[hh * 8 + 5] += bfhi(v[u][hh].z);
                acc[hh * 8 + 6] += bflo(v[u][hh].w);
                acc[hh * 8 + 7] += bfhi(v[u][hh].w);
            }
        }
    }

    // add base (bias - corr): chunk0 at 8l, chunk1 at 512+8l (clamped for pad)
    const int c1 = real1 ? (512 + 8 * l) : 0;
    float4 b00 = *(const float4*)(base + 8 * l);
    float4 b01 = *(const float4*)(base + 8 * l + 4);
    float4 b10 = *(const float4*)(base + c1);
    float4 b11 = *(const float4*)(base + c1 + 4);
    acc[0] += b00.x;  acc[1] += b00.y;  acc[2]  += b00.z;  acc[3]  += b00.w;
    acc[4] += b01.x;  acc[5] += b01.y;  acc[6]  += b01.z;  acc[7]  += b01.w;
    acc[8] += b10.x;  acc[9] += b10.y;  acc[10] += b10.z;  acc[11] += b10.w;
    acc[12] += b11.x; acc[13] += b11.y; acc[14] += b11.z;  acc[15] += b11.w;

    // wave max (masked)
    float m = -INFINITY;
    #pragma unroll
    for (int k = 0; k < 8; ++k) m = fmaxf(m, acc[k]);
    if (real1) {
        #pragma unroll
        for (int k = 8; k < 16; ++k) m = fmaxf(m, acc[k]);
    }
    #pragma unroll
    for (int off = 32; off > 0; off >>= 1)
        m = fmaxf(m, __shfl_xor(m, off, 64));

    // exp + wave sum (masked)
    float e[16];
    float ls = 0.0f;
    #pragma unroll
    for (int k = 0; k < 16; ++k) e[k] = __expf(acc[k] - m);
    #pragma unroll
    for (int k = 0; k < 8; ++k) ls += e[k];
    if (real1) {
        #pragma unroll
        for (int k = 8; k < 16; ++k) ls += e[k];
    }
    #pragma unroll
    for (int off = 32; off > 0; off >>= 1)
        ls += __shfl_xor(ls, off, 64);
    const float inv = 1.0f / ls;

    float* op = out + (size_t)(b0 + w) * NUM_CLASSES;
    *(float4*)(op + 8 * l)     = make_float4(e[0] * inv, e[1] * inv, e[2] * inv, e[3] * inv);
    *(float4*)(op + 8 * l + 4) = make_float4(e[4] * inv, e[5] * inv, e[6] * inv, e[7] * inv);
    if (real1) {
        *(float4*)(op + 512 + 8 * l)     = make_float4(e[8] * inv,  e[9] * inv,  e[10] * inv, e[11] * inv);
        *(float4*)(op + 512 + 8 * l + 4) = make_float4(e[12] * inv, e[13] * inv, e[14] * inv, e[15] * inv);
    }
}

extern "C" void kernel_launch(void* const* d_in, const int* in_sizes, int n_in,
                              void* d_out, int out_size, void* d_ws, size_t ws_size,
                              hipStream_t stream) {
    const float* x    = (const float*)d_in[0];  // (4096, 10000)
    const float* W    = (const float*)d_in[1];  // (10000, 1000)
    const float* bias = (const float*)d_in[2];  // (1000,)
    float* out = (float*)d_out;                 // (4096, 1000)

    char* ws = (char*)d_ws;
    float*        base = (float*)ws;                        // 4 KB
    float*        Sp   = (float*)(ws + 4096);               // 2 MB
    unsigned int* Wh   = (unsigned int*)(ws + 4096 + NUM_GROUPS * NSLICE * NUM_CLASSES * 4);
    // Wh: 10000 rows x 2048 B = 20.48 MB (padded to 1024 classes)
    int*          idxB = (int*)((char*)Wh + (size_t)TOTAL_ROWS * ROW_U2 * 8);

    k_stage<<<EXTRACT_BLOCKS + PREP_BLOCKS, 256, 0, stream>>>(W, x, Sp, Wh, idxB);
    k_combine<<<4, 256, 0, stream>>>(Sp, bias, base);
    k_gather<<<GATHER_BLOCKS, 256, 0, stream>>>(idxB, (const uint4*)Wh, base, out);
}

// Round 11
// 327.761 us; speedup vs baseline: 1.0321x; 1.0321x over previous
//
#include <hip/hip_runtime.h>
#include <math.h>

#define NUM_GROUPS 100
#define GROUP_SIZE 100
#define TOTAL_ROWS 10000
#define NUM_CLASSES 1000
#define BATCH 4096
#define SPB 16                     // samples per gather block (1 wave each)
#define GATHER_BLOCKS (BATCH / SPB)   // 256 = 1 block/CU = ONE generation
#define NSLICE 5
#define SLICE_ROWS (GROUP_SIZE / NSLICE)   // 20
#define ROW_U2 256                 // padded row: 1024 bf16 = 256 uint2 = 128 uint4
#define EXTRACT_BLOCKS 2500
#define PREP_BLOCKS (NUM_GROUPS * NSLICE)  // 500

// bf16 helpers: pack with RTNE, unpack via shift (bf16->fp32 is exact)
__device__ __forceinline__ unsigned int f2bf(float f) {
    unsigned int u = __float_as_uint(f);
    return (u + 0x7FFFu + ((u >> 16) & 1u)) >> 16;
}
__device__ __forceinline__ float bflo(unsigned int p) { return __uint_as_float(p << 16); }
__device__ __forceinline__ float bfhi(unsigned int p) { return __uint_as_float(p & 0xFFFF0000u); }

// ---------------------------------------------------------------------------
// k_stage: extract (blocks 0..2499) + prep (blocks 2500..2999), as R10.
// ---------------------------------------------------------------------------
__global__ __launch_bounds__(256)
void k_stage(const float* __restrict__ W, const float* __restrict__ x,
             float* __restrict__ Sp, unsigned int* __restrict__ Wh,
             int* __restrict__ idxB) {
    const int bid = blockIdx.x;
    const int tid = threadIdx.x;

    if (bid < EXTRACT_BLOCKS) {
        const float4* x4 = (const float4*)x;
        const int base = bid * 4096 + tid;
        #pragma unroll
        for (int k0 = 0; k0 < 16; k0 += 8) {
            float4 v[8];
            #pragma unroll
            for (int u = 0; u < 8; ++u)
                v[u] = x4[base + (k0 + u) * 256];
            #pragma unroll
            for (int u = 0; u < 8; ++u) {
                float4 vv = v[u];
                if (vv.x > 0.5f || vv.y > 0.5f || vv.z > 0.5f || vv.w > 0.5f) {
                    int i  = base + (k0 + u) * 256;
                    int b  = i / 2500;
                    int r4 = i - b * 2500;
                    int g  = r4 / 25;             // float4 never crosses a group
                    int j  = r4 * 4;
                    int val = vv.x > 0.5f ? j
                            : (vv.y > 0.5f ? j + 1 : (vv.z > 0.5f ? j + 2 : j + 3));
                    idxB[b * NUM_GROUPS + g] = val;
                }
            }
        }
    } else {
        const int pid = bid - EXTRACT_BLOCKS;     // 0..499
        const int g   = pid / NSLICE;
        const int h   = pid % NSLICE;
        const int r0  = h * SLICE_ROWS;

        const float4* Wr = (const float4*)(W + (size_t)(g * GROUP_SIZE + r0) * NUM_CLASSES);
        uint2* Whr = (uint2*)Wh + (size_t)(g * GROUP_SIZE + r0) * ROW_U2;

        if (tid < 250) {
            float4 s = make_float4(0.f, 0.f, 0.f, 0.f);
            #pragma unroll
            for (int k0 = 0; k0 < SLICE_ROWS; k0 += 5) {
                float4 v[5];
                #pragma unroll
                for (int u = 0; u < 5; ++u)
                    v[u] = Wr[(size_t)(k0 + u) * 250 + tid];
                #pragma unroll
                for (int u = 0; u < 5; ++u) {
                    float4 vv = v[u];
                    s.x += __expf(vv.x); s.y += __expf(vv.y);
                    s.z += __expf(vv.z); s.w += __expf(vv.w);
                    Whr[(size_t)(k0 + u) * ROW_U2 + tid] =
                        make_uint2(f2bf(vv.x) | (f2bf(vv.y) << 16),
                                   f2bf(vv.z) | (f2bf(vv.w) << 16));
                }
            }
            *(float4*)(Sp + (size_t)(g * NSLICE + h) * NUM_CLASSES + tid * 4) = s;
        }
        if (tid < SLICE_ROWS * 6) {               // zero pad classes 1000..1023
            int r = tid / 6, p = 250 + tid % 6;
            Whr[(size_t)r * ROW_U2 + p] = make_uint2(0u, 0u);
        }
    }
}

// ---------------------------------------------------------------------------
// k_combine: base[c] = bias[c] - sum_g log(sum_h Sp[g,h,c]).
// ---------------------------------------------------------------------------
__global__ __launch_bounds__(256)
void k_combine(const float* __restrict__ Sp, const float* __restrict__ bias,
               float* __restrict__ base) {
    const int c = blockIdx.x * 250 + threadIdx.x;
    if (threadIdx.x >= 250 || c >= NUM_CLASSES) return;
    float acc = bias[c];
    #pragma unroll 4
    for (int g = 0; g < NUM_GROUPS; ++g) {
        const float* p = Sp + (size_t)g * NSLICE * NUM_CLASSES + c;
        float S = p[0];
        #pragma unroll
        for (int h = 1; h < NSLICE; ++h) S += p[h * NUM_CLASSES];
        acc -= __logf(S);
    }
    base[c] = acc;
}

// ---------------------------------------------------------------------------
// k_gather: 256 blocks x 1024 threads (16 waves = 16 samples; 1 block/CU,
// one generation, 16 waves/CU as before). L2-LOCALITY version: a
// __syncthreads() per 4-group chunk keeps all 16 waves of the CU on the
// same ~200 KB group-slab; with all 256 blocks co-launched, the per-XCD
// working set stays inside the 4 MB L2 window (20.5 MB table would
// otherwise thrash it via wave drift -> L3). Loads are issued BEFORE the
// barrier, consumed after -> latency still hidden across the barrier.
// Row ids in 2 VGPRs/wave, broadcast via readlane with the uniform loop
// index (no LDS reads, loop not fully unrolled -> small I-footprint).
// ---------------------------------------------------------------------------
__global__ __launch_bounds__(1024, 1)
void k_gather(const int* __restrict__ idxB, const uint4* __restrict__ Wh4,
              const float* __restrict__ base, float* __restrict__ out) {
    const int tid = threadIdx.x;
    const int w   = tid >> 6;                     // wave = sample (0..15)
    const int l   = tid & 63;
    const int b0  = blockIdx.x * SPB;
    const bool real1 = (l <= 60);                 // chunk1 lanes 61-63 are pad

    // this sample's 100 row-ids -> 2 VGPRs (coalesced dword loads)
    const int* myidx = idxB + (size_t)(b0 + w) * NUM_GROUPS;
    const int idxlo = myidx[l];                            // groups 0..63
    const int idxhi = myidx[(l < 36) ? (64 + l) : 63];     // groups 64..99

    float acc[16];
    #pragma unroll
    for (int k = 0; k < 16; ++k) acc[k] = 0.0f;

    for (int g = 0; g < NUM_GROUPS; g += 4) {     // 25 chunks; 100=64+36 so a
        uint4 v[4][2];                            // chunk never straddles lo/hi
        #pragma unroll
        for (int u = 0; u < 4; ++u) {
            int gg = g + u;                       // wave-uniform
            int r = (gg < 64) ? __builtin_amdgcn_readlane(idxlo, gg)
                              : __builtin_amdgcn_readlane(idxhi, gg - 64);
            const uint4* row = Wh4 + (size_t)r * 128;
            v[u][0] = row[l];
            v[u][1] = row[l + 64];
        }
        __syncthreads();                          // keep 16 waves in phase;
                                                  // loads already in flight
        #pragma unroll
        for (int u = 0; u < 4; ++u) {
            #pragma unroll
            for (int hh = 0; hh < 2; ++hh) {
                acc[hh * 8 + 0] += bflo(v[u][hh].x);
                acc[hh * 8 + 1] += bfhi(v[u][hh].x);
                acc[hh * 8 + 2] += bflo(v[u][hh].y);
                acc[hh * 8 + 3] += bfhi(v[u][hh].y);
                acc[hh * 8 + 4] += bflo(v[u][hh].z);
                acc[hh * 8 + 5] += bfhi(v[u][hh].z);
                acc[hh * 8 + 6] += bflo(v[u][hh].w);
                acc[hh * 8 + 7] += bfhi(v[u][hh].w);
            }
        }
    }

    // add base (bias - corr): chunk0 at 8l, chunk1 at 512+8l (clamped for pad)
    const int c1 = real1 ? (512 + 8 * l) : 0;
    float4 b00 = *(const float4*)(base + 8 * l);
    float4 b01 = *(const float4*)(base + 8 * l + 4);
    float4 b10 = *(const float4*)(base + c1);
    float4 b11 = *(const float4*)(base + c1 + 4);
    acc[0] += b00.x;  acc[1] += b00.y;  acc[2]  += b00.z;  acc[3]  += b00.w;
    acc[4] += b01.x;  acc[5] += b01.y;  acc[6]  += b01.z;  acc[7]  += b01.w;
    acc[8] += b10.x;  acc[9] += b10.y;  acc[10] += b10.z;  acc[11] += b10.w;
    acc[12] += b11.x; acc[13] += b11.y; acc[14] += b11.z;  acc[15] += b11.w;

    // wave max (masked)
    float m = -INFINITY;
    #pragma unroll
    for (int k = 0; k < 8; ++k) m = fmaxf(m, acc[k]);
    if (real1) {
        #pragma unroll
        for (int k = 8; k < 16; ++k) m = fmaxf(m, acc[k]);
    }
    #pragma unroll
    for (int off = 32; off > 0; off >>= 1)
        m = fmaxf(m, __shfl_xor(m, off, 64));

    // exp + wave sum (masked)
    float e[16];
    float ls = 0.0f;
    #pragma unroll
    for (int k = 0; k < 16; ++k) e[k] = __expf(acc[k] - m);
    #pragma unroll
    for (int k = 0; k < 8; ++k) ls += e[k];
    if (real1) {
        #pragma unroll
        for (int k = 8; k < 16; ++k) ls += e[k];
    }
    #pragma unroll
    for (int off = 32; off > 0; off >>= 1)
        ls += __shfl_xor(ls, off, 64);
    const float inv = 1.0f / ls;

    float* op = out + (size_t)(b0 + w) * NUM_CLASSES;
    *(float4*)(op + 8 * l)     = make_float4(e[0] * inv, e[1] * inv, e[2] * inv, e[3] * inv);
    *(float4*)(op + 8 * l + 4) = make_float4(e[4] * inv, e[5] * inv, e[6] * inv, e[7] * inv);
    if (real1) {
        *(float4*)(op + 512 + 8 * l)     = make_float4(e[8] * inv,  e[9] * inv,  e[10] * inv, e[11] * inv);
        *(float4*)(op + 512 + 8 * l + 4) = make_float4(e[12] * inv, e[13] * inv, e[14] * inv, e[15] * inv);
    }
}

extern "C" void kernel_launch(void* const* d_in, const int* in_sizes, int n_in,
                              void* d_out, int out_size, void* d_ws, size_t ws_size,
                              hipStream_t stream) {
    const float* x    = (const float*)d_in[0];  // (4096, 10000)
    const float* W    = (const float*)d_in[1];  // (10000, 1000)
    const float* bias = (const float*)d_in[2];  // (1000,)
    float* out = (float*)d_out;                 // (4096, 1000)

    char* ws = (char*)d_ws;
    float*        base = (float*)ws;                        // 4 KB
    float*        Sp   = (float*)(ws + 4096);               // 2 MB
    unsigned int* Wh   = (unsigned int*)(ws + 4096 + NUM_GROUPS * NSLICE * NUM_CLASSES * 4);
    // Wh: 10000 rows x 2048 B = 20.48 MB (padded to 1024 classes)
    int*          idxB = (int*)((char*)Wh + (size_t)TOTAL_ROWS * ROW_U2 * 8);

    k_stage<<<EXTRACT_BLOCKS + PREP_BLOCKS, 256, 0, stream>>>(W, x, Sp, Wh, idxB);
    k_combine<<<4, 256, 0, stream>>>(Sp, bias, base);
    k_gather<<<GATHER_BLOCKS, 1024, 0, stream>>>(idxB, (const uint4*)Wh, base, out);
}